// Round 2
// baseline (986.502 us; speedup 1.0000x reference)
//
#include <hip/hip_runtime.h>

// Problem constants
#define Bb 8
#define Cc 64
#define ICc 32
#define Wd 64
#define Hd 64
#define Zd 32
#define WHZ 131072      // Wd*Hd*Zd
#define HZ 2048         // Hd*Zd
#define NPIXEL 32768    // Bb*Wd*Hd
#define NPOSN 1048576   // Bb*Wd*Hd*Zd
#define K1_BLK 2048
#define K1_WAVES 4096   // K1_BLK * 2 waves
#define NPIX 8          // pixels per wave

typedef unsigned short ushort_t;
typedef unsigned int uint_t;

__device__ __forceinline__ float bf2f(ushort_t u) {
    return __uint_as_float(((uint_t)u) << 16);
}
__device__ __forceinline__ ushort_t f2bf(float f) {
    uint_t x = __float_as_uint(f);
    uint_t r = (x + 0x7fffu + ((x >> 16) & 1u)) >> 16;  // round-to-nearest-even
    return (ushort_t)r;
}

// ---------------------------------------------------------------------------
// K1: per-pixel fused projections + attention. One wave = one pixel at a time.
// Writes y (b,w,h,z,ic) as bf16, and per-wave partial sums of wy / wy^2.
// ---------------------------------------------------------------------------
__global__ __launch_bounds__(128)
void k1_attn(const float* __restrict__ x,
             const float* __restrict__ Wg, const float* __restrict__ bg,
             const float* __restrict__ Wt, const float* __restrict__ bt,
             const float* __restrict__ Wp, const float* __restrict__ bp,
             const float* __restrict__ Ww, const float* __restrict__ bw,
             ushort_t* __restrict__ y_out,
             float* __restrict__ partials)
{
    __shared__ ushort_t Wt_s[64][32];   // [c][ic] bf16
    __shared__ ushort_t Wp_s[64][32];
    __shared__ ushort_t Wg_s[64][32];
    __shared__ float Ww_s[64][32];      // [c][ic] fp32
    __shared__ float bt_s[32], bp_s[32], bg_s[32], bw_s[64];
    __shared__ float x_s[2][64][36];    // per-wave x slab, stride 36 (16B-aligned, conflict-free)
    __shared__ float th_s[2][32][33];   // theta [ic][z], stride 33
    __shared__ float ph_s[2][32][20];   // phi pooled [ic][nz], stride 20 (16B-aligned reads)
    __shared__ float gp_s[2][16][32];   // g pooled [nz][ic]

    const int tid = threadIdx.x;
    for (int idx = tid; idx < 2048; idx += 128) {
        const int wic = idx >> 6, wc = idx & 63;
        Wt_s[wc][wic] = f2bf(Wt[idx]);
        Wp_s[wc][wic] = f2bf(Wp[idx]);
        Wg_s[wc][wic] = f2bf(Wg[idx]);
        Ww_s[idx >> 5][idx & 31] = Ww[idx];   // Ww is (64,32) row-major already
    }
    if (tid < 32) { bt_s[tid] = bt[tid]; bp_s[tid] = bp[tid]; bg_s[tid] = bg[tid]; }
    if (tid < 64) bw_s[tid] = bw[tid];
    __syncthreads();

    const int lane = tid & 63;
    const int wv   = tid >> 6;
    const int wid  = blockIdx.x * 2 + wv;

    const int ic  = lane & 31;   // projection-phase mapping
    const int hh  = lane >> 5;
    const int z0  = hh * 16;
    const int zl  = lane & 31;   // attention-phase mapping
    const int grp = lane >> 5;
    const int nz0 = grp * 8;

    float wys[32], wysq[32];
    #pragma unroll
    for (int i = 0; i < 32; ++i) { wys[i] = 0.f; wysq[i] = 0.f; }

    const float btr = bt_s[ic], bpr = bp_s[ic], bgr = bg_s[ic];

    for (int it = 0; it < NPIX; ++it) {
        const int p  = wid * NPIX + it;
        const int pb = p >> 12;
        const int pw = (p >> 6) & 63;
        const int phx = p & 63;
        const size_t xbase = (size_t)pb * (Cc * WHZ) + (size_t)pw * HZ + (size_t)phx * Zd;

        // Phase 1: stage x slab (64 ch x 32 z)
        #pragma unroll
        for (int k = 0; k < 8; ++k) {
            const int idx = k * 64 + lane;
            const int c = idx >> 3, q = idx & 7;
            const float4 v = *reinterpret_cast<const float4*>(x + xbase + (size_t)c * WHZ + q * 4);
            *reinterpret_cast<float4*>(&x_s[wv][c][q * 4]) = v;
        }
        __syncthreads();

        // Phase 2: projections. lane -> (ic, z-half)
        float th[16], ph2[16], gg[16];
        #pragma unroll
        for (int j = 0; j < 16; ++j) { th[j] = btr; ph2[j] = bpr; gg[j] = bgr; }

        for (int c = 0; c < 64; ++c) {
            const float wt = bf2f(Wt_s[c][ic]);
            const float wp = bf2f(Wp_s[c][ic]);
            const float wg = bf2f(Wg_s[c][ic]);
            const float4 a0 = *reinterpret_cast<const float4*>(&x_s[wv][c][z0]);
            const float4 a1 = *reinterpret_cast<const float4*>(&x_s[wv][c][z0 + 4]);
            const float4 a2 = *reinterpret_cast<const float4*>(&x_s[wv][c][z0 + 8]);
            const float4 a3 = *reinterpret_cast<const float4*>(&x_s[wv][c][z0 + 12]);
            const float xv[16] = {a0.x,a0.y,a0.z,a0.w, a1.x,a1.y,a1.z,a1.w,
                                  a2.x,a2.y,a2.z,a2.w, a3.x,a3.y,a3.z,a3.w};
            #pragma unroll
            for (int j = 0; j < 16; ++j) {
                th[j]  = fmaf(wt, xv[j], th[j]);
                ph2[j] = fmaf(wp, xv[j], ph2[j]);
                gg[j]  = fmaf(wg, xv[j], gg[j]);
            }
        }

        // Phase 3: pool (z-pairs) + stage to LDS
        #pragma unroll
        for (int j = 0; j < 16; ++j) th_s[wv][ic][z0 + j] = th[j];
        #pragma unroll
        for (int j = 0; j < 8; ++j) {
            ph_s[wv][ic][hh * 8 + j] = fmaxf(ph2[2*j], ph2[2*j+1]);
            gp_s[wv][hh * 8 + j][ic] = fmaxf(gg[2*j], gg[2*j+1]);
        }
        __syncthreads();

        // Phase 4: f = theta^T @ phi  (lane -> (z, nz-half)), then softmax over nz
        float thr[32];
        #pragma unroll
        for (int i = 0; i < 32; ++i) thr[i] = th_s[wv][i][zl];

        float f[8];
        #pragma unroll
        for (int j = 0; j < 8; ++j) f[j] = 0.f;
        for (int i = 0; i < 32; ++i) {
            const float4 pa  = *reinterpret_cast<const float4*>(&ph_s[wv][i][nz0]);
            const float4 pb4 = *reinterpret_cast<const float4*>(&ph_s[wv][i][nz0 + 4]);
            const float t = thr[i];
            f[0] = fmaf(t, pa.x,  f[0]); f[1] = fmaf(t, pa.y,  f[1]);
            f[2] = fmaf(t, pa.z,  f[2]); f[3] = fmaf(t, pa.w,  f[3]);
            f[4] = fmaf(t, pb4.x, f[4]); f[5] = fmaf(t, pb4.y, f[5]);
            f[6] = fmaf(t, pb4.z, f[6]); f[7] = fmaf(t, pb4.w, f[7]);
        }

        float m = f[0];
        #pragma unroll
        for (int j = 1; j < 8; ++j) m = fmaxf(m, f[j]);
        m = fmaxf(m, __shfl_xor(m, 32, 64));
        float ssum = 0.f;
        #pragma unroll
        for (int j = 0; j < 8; ++j) { f[j] = __expf(f[j] - m); ssum += f[j]; }
        ssum += __shfl_xor(ssum, 32, 64);
        const float rs = 1.0f / ssum;

        // Phase 5: y = P @ g  (sum over nz; halves hold 8 nz each -> xor-32 reduce)
        float y[32];
        #pragma unroll
        for (int i = 0; i < 32; ++i) y[i] = 0.f;
        #pragma unroll
        for (int j = 0; j < 8; ++j) {
            const float pj = f[j] * rs;
            const float* gr = &gp_s[wv][nz0 + j][0];
            #pragma unroll
            for (int i = 0; i < 32; i += 4) {
                const float4 g4 = *reinterpret_cast<const float4*>(gr + i);
                y[i]   = fmaf(pj, g4.x, y[i]);
                y[i+1] = fmaf(pj, g4.y, y[i+1]);
                y[i+2] = fmaf(pj, g4.z, y[i+2]);
                y[i+3] = fmaf(pj, g4.w, y[i+3]);
            }
        }
        #pragma unroll
        for (int i = 0; i < 32; ++i) y[i] += __shfl_xor(y[i], 32, 64);

        // Round to bf16 now so K1 stats match K3's conv input exactly
        ushort_t yb[32];
        #pragma unroll
        for (int i = 0; i < 32; ++i) { yb[i] = f2bf(y[i]); y[i] = bf2f(yb[i]); }

        // Phase 6: store y (bf16). lane (zl,grp) stores ic = grp*16..grp*16+15
        {
            uint_t pk[8];
            #pragma unroll
            for (int i2 = 0; i2 < 8; ++i2) {
                const uint_t lo_ = (uint_t)yb[2*i2]      | ((uint_t)yb[2*i2+1]  << 16);
                const uint_t hi_ = (uint_t)yb[16 + 2*i2] | ((uint_t)yb[17 + 2*i2] << 16);
                pk[i2] = grp ? hi_ : lo_;   // static indexing; runtime select
            }
            uint4* dst = reinterpret_cast<uint4*>(y_out + ((size_t)p * 32 + zl) * 32 + grp * 16);
            dst[0] = make_uint4(pk[0], pk[1], pk[2], pk[3]);
            dst[1] = make_uint4(pk[4], pk[5], pk[6], pk[7]);
        }

        // Phase 7: wy = Ww @ y + bw; accumulate stats. lane covers c = grp*32..+31
        #pragma unroll
        for (int i = 0; i < 32; ++i) {
            const int c = grp * 32 + i;
            float acc = bw_s[c];
            const float* wr = &Ww_s[c][0];
            #pragma unroll
            for (int k = 0; k < 32; k += 4) {
                const float4 w4 = *reinterpret_cast<const float4*>(wr + k);
                acc = fmaf(w4.x, y[k],   acc);
                acc = fmaf(w4.y, y[k+1], acc);
                acc = fmaf(w4.z, y[k+2], acc);
                acc = fmaf(w4.w, y[k+3], acc);
            }
            wys[i]  += acc;
            wysq[i]  = fmaf(acc, acc, wysq[i]);
        }
    }

    // Reduce stats over the 32 z-lanes (xor bits 0..4), then write one column
    #pragma unroll
    for (int off = 1; off <= 16; off <<= 1) {
        #pragma unroll
        for (int i = 0; i < 32; ++i) {
            wys[i]  += __shfl_xor(wys[i],  off, 64);
            wysq[i] += __shfl_xor(wysq[i], off, 64);
        }
    }
    if (zl == 0) {
        #pragma unroll
        for (int i = 0; i < 32; ++i) {
            const int c = grp * 32 + i;
            partials[(size_t)c * K1_WAVES + wid]        = wys[i];
            partials[(size_t)(64 + c) * K1_WAVES + wid] = wysq[i];
        }
    }
}

// ---------------------------------------------------------------------------
// K2: finalize BN stats; fold BN affine into the final conv weights/bias.
// One block per channel c.
// ---------------------------------------------------------------------------
__global__ __launch_bounds__(256)
void k2_stats(const float* __restrict__ partials,
              const float* __restrict__ Ww, const float* __restrict__ bw,
              const float* __restrict__ gamma, const float* __restrict__ beta,
              float* __restrict__ wws, float* __restrict__ bias2)
{
    __shared__ float red[256];
    const int c = blockIdx.x;
    const int t = threadIdx.x;

    float s = 0.f;
    for (int k = t; k < K1_WAVES; k += 256) s += partials[(size_t)c * K1_WAVES + k];
    red[t] = s; __syncthreads();
    for (int o = 128; o > 0; o >>= 1) { if (t < o) red[t] += red[t + o]; __syncthreads(); }
    const float S = red[0]; __syncthreads();

    float q = 0.f;
    for (int k = t; k < K1_WAVES; k += 256) q += partials[(size_t)(64 + c) * K1_WAVES + k];
    red[t] = q; __syncthreads();
    for (int o = 128; o > 0; o >>= 1) { if (t < o) red[t] += red[t + o]; __syncthreads(); }
    const float SS = red[0];

    const float invN = 1.0f / (float)NPOSN;
    const float mean = S * invN;
    const float var  = SS * invN - mean * mean;
    const float scale = gamma[c] * rsqrtf(var + 1e-5f);
    const float shift = beta[c] - mean * scale;
    if (t < 32) wws[c * 32 + t] = Ww[c * 32 + t] * scale;
    if (t == 0) bias2[c] = bw[c] * scale + shift;
}

// ---------------------------------------------------------------------------
// K3: out = (folded conv)(y) + x.  64 positions per block, coalesced.
// ---------------------------------------------------------------------------
__global__ __launch_bounds__(256)
void k3_out(const ushort_t* __restrict__ y,
            const float* __restrict__ wws, const float* __restrict__ bias2,
            const float* __restrict__ x, float* __restrict__ out)
{
    __shared__ float y_s[64][33];
    __shared__ float ww_s[64][32];
    __shared__ float b2_s[64];
    const int t = threadIdx.x;
    for (int idx = t; idx < 2048; idx += 256) ww_s[idx >> 5][idx & 31] = wws[idx];
    if (t < 64) b2_s[t] = bias2[t];

    const size_t pos0 = (size_t)blockIdx.x * 64;
    {
        const uint4 v = *reinterpret_cast<const uint4*>(y + pos0 * 32 + (size_t)t * 8);
        const int pl = t >> 2, e0 = (t & 3) * 8;
        const uint_t vv[4] = {v.x, v.y, v.z, v.w};
        #pragma unroll
        for (int k = 0; k < 4; ++k) {
            y_s[pl][e0 + 2*k]     = bf2f((ushort_t)(vv[k] & 0xffffu));
            y_s[pl][e0 + 2*k + 1] = bf2f((ushort_t)(vv[k] >> 16));
        }
    }
    __syncthreads();

    const int pl = t & 63;
    const int cg = t >> 6;
    const size_t pos = pos0 + pl;
    const size_t pix = pos >> 5;
    const int z   = (int)(pos & 31);
    const int pb  = (int)(pix >> 12);
    const int pw  = (int)((pix >> 6) & 63);
    const int phx = (int)(pix & 63);
    const size_t base = (size_t)pb * (Cc * WHZ) + (size_t)pw * HZ + (size_t)phx * Zd + (size_t)z;

    float yv[32];
    #pragma unroll
    for (int i = 0; i < 32; ++i) yv[i] = y_s[pl][i];

    #pragma unroll
    for (int i = 0; i < 16; ++i) {
        const int c = cg * 16 + i;
        float acc = b2_s[c];
        const float* wr = &ww_s[c][0];
        #pragma unroll
        for (int k = 0; k < 32; k += 4) {
            const float4 w4 = *reinterpret_cast<const float4*>(wr + k);
            acc = fmaf(w4.x, yv[k],   acc);
            acc = fmaf(w4.y, yv[k+1], acc);
            acc = fmaf(w4.z, yv[k+2], acc);
            acc = fmaf(w4.w, yv[k+3], acc);
        }
        const size_t off = base + (size_t)c * WHZ;
        out[off] = acc + x[off];
    }
}

// ---------------------------------------------------------------------------
extern "C" void kernel_launch(void* const* d_in, const int* in_sizes, int n_in,
                              void* d_out, int out_size, void* d_ws, size_t ws_size,
                              hipStream_t stream)
{
    const float* x     = (const float*)d_in[0];
    // d_in[1] = spacings (unused by reference)
    const float* Wg    = (const float*)d_in[2];
    const float* bg    = (const float*)d_in[3];
    const float* Wt    = (const float*)d_in[4];
    const float* bt    = (const float*)d_in[5];
    const float* Wp    = (const float*)d_in[6];
    const float* bp    = (const float*)d_in[7];
    const float* Ww    = (const float*)d_in[8];
    const float* bw    = (const float*)d_in[9];
    const float* gamma = (const float*)d_in[10];
    const float* beta  = (const float*)d_in[11];
    float* out = (float*)d_out;

    // Workspace layout
    ushort_t* y_ws   = (ushort_t*)d_ws;                                   // 64 MiB (bf16 y)
    float* partials  = (float*)((char*)d_ws + (size_t)33554432 * 2);      // 2 MiB
    float* wws       = (float*)((char*)partials + (size_t)128 * K1_WAVES * 4); // 8 KiB
    float* bias2     = wws + 2048;

    k1_attn<<<K1_BLK, 128, 0, stream>>>(x, Wg, bg, Wt, bt, Wp, bp, Ww, bw, y_ws, partials);
    k2_stats<<<64, 256, 0, stream>>>(partials, Ww, bw, gamma, beta, wws, bias2);
    k3_out<<<NPOSN / 64, 256, 0, stream>>>(y_ws, wws, bias2, x, out);
}

// Round 3
// 854.980 us; speedup vs baseline: 1.1538x; 1.1538x over previous
//
#include <hip/hip_runtime.h>

// Problem constants
#define Bb 8
#define Cc 64
#define ICc 32
#define Wd 64
#define Hd 64
#define Zd 32
#define WHZ 131072      // Wd*Hd*Zd
#define HZ 2048         // Hd*Zd
#define NPIXEL 32768    // Bb*Wd*Hd
#define NPOSN 1048576   // Bb*Wd*Hd*Zd
#define K1_BLK 2048
#define K1_WAVES 4096   // K1_BLK * 2 waves
#define NPIX 8          // pixels per wave

typedef unsigned short ushort_t;
typedef unsigned int uint_t;

__device__ __forceinline__ float bf2f(ushort_t u) {
    return __uint_as_float(((uint_t)u) << 16);
}
__device__ __forceinline__ ushort_t f2bf(float f) {
    uint_t x = __float_as_uint(f);
    uint_t r = (x + 0x7fffu + ((x >> 16) & 1u)) >> 16;  // round-to-nearest-even
    return (ushort_t)r;
}

// Wave-local LDS fence: all loop LDS buffers are wave-private; same-wave DS ops
// execute in order, so a compiler-visible lgkmcnt drain replaces __syncthreads.
#define WAVE_FENCE() asm volatile("s_waitcnt lgkmcnt(0)" ::: "memory")

// ---------------------------------------------------------------------------
// K1: per-pixel fused projections + attention. One wave = one pixel at a time.
// Writes y (b,w,h,z,ic) as bf16, and per-wave partial sums of wy / wy^2.
// LDS: 38784 B/block -> 4 blocks/CU -> 2 waves/SIMD (vs 1 before).
// ---------------------------------------------------------------------------
__global__ __launch_bounds__(128)
void k1_attn(const float* __restrict__ x,
             const float* __restrict__ Wg, const float* __restrict__ bg,
             const float* __restrict__ Wt, const float* __restrict__ bt,
             const float* __restrict__ Wp, const float* __restrict__ bp,
             const float* __restrict__ Ww, const float* __restrict__ bw,
             ushort_t* __restrict__ y_out,
             float* __restrict__ partials)
{
    __shared__ uint_t  Wtp_s[64][32];   // [c][ic] packed (bf16 wt | wp<<16)
    __shared__ ushort_t Wg_s[64][32];   // [c][ic] bf16
    __shared__ float   Ww_s[64][32];    // [c][ic] fp32
    __shared__ float bt_s[32], bp_s[32], bg_s[32], bw_s[64];
    // Per-wave scratch, 2208 floats = 8832 B. Two aliased layouts:
    //   phase 1-2: x slab   [64][32]            (2048 floats)
    //   phase 3-5: th[32][33] | ph[32][20] | gp[16][32]  (1056+640+512=2208)
    __shared__ float pw[2][2208];

    const int tid = threadIdx.x;
    for (int idx = tid; idx < 2048; idx += 128) {
        const int wic = idx >> 6, wc = idx & 63;
        Wtp_s[wc][wic] = (uint_t)f2bf(Wt[idx]) | ((uint_t)f2bf(Wp[idx]) << 16);
        Wg_s[wc][wic]  = f2bf(Wg[idx]);
        Ww_s[idx >> 5][idx & 31] = Ww[idx];   // Ww is (64,32) row-major already
    }
    if (tid < 32) { bt_s[tid] = bt[tid]; bp_s[tid] = bp[tid]; bg_s[tid] = bg[tid]; }
    if (tid < 64) bw_s[tid] = bw[tid];
    __syncthreads();   // weights shared by both waves; only barrier in the kernel

    const int lane = tid & 63;
    const int wv   = tid >> 6;
    const int wid  = blockIdx.x * 2 + wv;

    float* const xs  = pw[wv];          // [64][32]
    float* const ths = pw[wv];          // [32][33], aliases xs
    float* const phs = pw[wv] + 1056;   // [32][20]
    float* const gps = pw[wv] + 1696;   // [16][32]

    const int ic  = lane & 31;   // projection-phase mapping
    const int hh  = lane >> 5;
    const int z0  = hh * 16;
    const int zl  = lane & 31;   // attention-phase mapping
    const int grp = lane >> 5;
    const int nz0 = grp * 8;

    float wys[32], wysq[32];
    #pragma unroll
    for (int i = 0; i < 32; ++i) { wys[i] = 0.f; wysq[i] = 0.f; }

    const float btr = bt_s[ic], bpr = bp_s[ic], bgr = bg_s[ic];

    for (int it = 0; it < NPIX; ++it) {
        const int p  = wid * NPIX + it;
        const int pb = p >> 12;
        const int pw_ = (p >> 6) & 63;
        const int phx = p & 63;
        const size_t xbase = (size_t)pb * (Cc * WHZ) + (size_t)pw_ * HZ + (size_t)phx * Zd;

        // Phase 1: stage x slab (64 ch x 32 z). Linear lane*16B -> conflict-free.
        WAVE_FENCE();   // prev-iter proj-buffer reads drained before overwrite
        #pragma unroll
        for (int k = 0; k < 8; ++k) {
            const int idx = k * 64 + lane;
            const int c = idx >> 3, q = idx & 7;
            const float4 v = *reinterpret_cast<const float4*>(x + xbase + (size_t)c * WHZ + q * 4);
            *reinterpret_cast<float4*>(xs + idx * 4) = v;
        }
        WAVE_FENCE();

        // Phase 2: projections. lane -> (ic, z-half). x reads are broadcast.
        float th[16], ph2[16], gg[16];
        #pragma unroll
        for (int j = 0; j < 16; ++j) { th[j] = btr; ph2[j] = bpr; gg[j] = bgr; }

        for (int c = 0; c < 64; ++c) {
            const uint_t wtp = Wtp_s[c][ic];
            const float wt = bf2f((ushort_t)(wtp & 0xffffu));
            const float wp = bf2f((ushort_t)(wtp >> 16));
            const float wg = bf2f(Wg_s[c][ic]);
            const float* xr = xs + c * 32 + z0;
            const float4 a0 = *reinterpret_cast<const float4*>(xr);
            const float4 a1 = *reinterpret_cast<const float4*>(xr + 4);
            const float4 a2 = *reinterpret_cast<const float4*>(xr + 8);
            const float4 a3 = *reinterpret_cast<const float4*>(xr + 12);
            const float xv[16] = {a0.x,a0.y,a0.z,a0.w, a1.x,a1.y,a1.z,a1.w,
                                  a2.x,a2.y,a2.z,a2.w, a3.x,a3.y,a3.z,a3.w};
            #pragma unroll
            for (int j = 0; j < 16; ++j) {
                th[j]  = fmaf(wt, xv[j], th[j]);
                ph2[j] = fmaf(wp, xv[j], ph2[j]);
                gg[j]  = fmaf(wg, xv[j], gg[j]);
            }
        }

        // Phase 3: pool (z-pairs) + stage to LDS (overlays the x slab)
        WAVE_FENCE();   // x reads drained before aliased writes
        #pragma unroll
        for (int j = 0; j < 16; ++j) ths[ic * 33 + z0 + j] = th[j];
        #pragma unroll
        for (int j = 0; j < 8; ++j) {
            phs[ic * 20 + hh * 8 + j] = fmaxf(ph2[2*j], ph2[2*j+1]);
            gps[(hh * 8 + j) * 32 + ic] = fmaxf(gg[2*j], gg[2*j+1]);
        }
        WAVE_FENCE();

        // Phase 4: f = theta^T @ phi  (lane -> (z, nz-half)), then softmax over nz
        float thr[32];
        #pragma unroll
        for (int i = 0; i < 32; ++i) thr[i] = ths[i * 33 + zl];

        float f[8];
        #pragma unroll
        for (int j = 0; j < 8; ++j) f[j] = 0.f;
        for (int i = 0; i < 32; ++i) {
            const float4 pa  = *reinterpret_cast<const float4*>(phs + i * 20 + nz0);
            const float4 pb4 = *reinterpret_cast<const float4*>(phs + i * 20 + nz0 + 4);
            const float t = thr[i];
            f[0] = fmaf(t, pa.x,  f[0]); f[1] = fmaf(t, pa.y,  f[1]);
            f[2] = fmaf(t, pa.z,  f[2]); f[3] = fmaf(t, pa.w,  f[3]);
            f[4] = fmaf(t, pb4.x, f[4]); f[5] = fmaf(t, pb4.y, f[5]);
            f[6] = fmaf(t, pb4.z, f[6]); f[7] = fmaf(t, pb4.w, f[7]);
        }

        float m = f[0];
        #pragma unroll
        for (int j = 1; j < 8; ++j) m = fmaxf(m, f[j]);
        m = fmaxf(m, __shfl_xor(m, 32, 64));
        float ssum = 0.f;
        #pragma unroll
        for (int j = 0; j < 8; ++j) { f[j] = __expf(f[j] - m); ssum += f[j]; }
        ssum += __shfl_xor(ssum, 32, 64);
        const float rs = 1.0f / ssum;

        // Phase 5: y = P @ g  (sum over nz; halves hold 8 nz each -> xor-32 reduce)
        float y[32];
        #pragma unroll
        for (int i = 0; i < 32; ++i) y[i] = 0.f;
        #pragma unroll
        for (int j = 0; j < 8; ++j) {
            const float pj = f[j] * rs;
            const float* gr = gps + (nz0 + j) * 32;
            #pragma unroll
            for (int i = 0; i < 32; i += 4) {
                const float4 g4 = *reinterpret_cast<const float4*>(gr + i);
                y[i]   = fmaf(pj, g4.x, y[i]);
                y[i+1] = fmaf(pj, g4.y, y[i+1]);
                y[i+2] = fmaf(pj, g4.z, y[i+2]);
                y[i+3] = fmaf(pj, g4.w, y[i+3]);
            }
        }
        #pragma unroll
        for (int i = 0; i < 32; ++i) y[i] += __shfl_xor(y[i], 32, 64);

        // Round to bf16 now so K1 stats match K3's conv input exactly
        ushort_t yb[32];
        #pragma unroll
        for (int i = 0; i < 32; ++i) { yb[i] = f2bf(y[i]); y[i] = bf2f(yb[i]); }

        // Phase 6: store y (bf16). lane (zl,grp) stores ic = grp*16..grp*16+15
        {
            uint_t pk[8];
            #pragma unroll
            for (int i2 = 0; i2 < 8; ++i2) {
                const uint_t lo_ = (uint_t)yb[2*i2]      | ((uint_t)yb[2*i2+1]  << 16);
                const uint_t hi_ = (uint_t)yb[16 + 2*i2] | ((uint_t)yb[17 + 2*i2] << 16);
                pk[i2] = grp ? hi_ : lo_;   // static indexing; runtime select
            }
            uint4* dst = reinterpret_cast<uint4*>(y_out + ((size_t)p * 32 + zl) * 32 + grp * 16);
            dst[0] = make_uint4(pk[0], pk[1], pk[2], pk[3]);
            dst[1] = make_uint4(pk[4], pk[5], pk[6], pk[7]);
        }

        // Phase 7: wy = Ww @ y + bw; accumulate stats. lane covers c = grp*32..+31
        #pragma unroll
        for (int i = 0; i < 32; ++i) {
            const int c = grp * 32 + i;
            float acc = bw_s[c];
            const float* wr = &Ww_s[c][0];
            #pragma unroll
            for (int k = 0; k < 32; k += 4) {
                const float4 w4 = *reinterpret_cast<const float4*>(wr + k);
                acc = fmaf(w4.x, y[k],   acc);
                acc = fmaf(w4.y, y[k+1], acc);
                acc = fmaf(w4.z, y[k+2], acc);
                acc = fmaf(w4.w, y[k+3], acc);
            }
            wys[i]  += acc;
            wysq[i]  = fmaf(acc, acc, wysq[i]);
        }
    }

    // Reduce stats over the 32 z-lanes (xor bits 0..4), then write one column
    #pragma unroll
    for (int off = 1; off <= 16; off <<= 1) {
        #pragma unroll
        for (int i = 0; i < 32; ++i) {
            wys[i]  += __shfl_xor(wys[i],  off, 64);
            wysq[i] += __shfl_xor(wysq[i], off, 64);
        }
    }
    if (zl == 0) {
        #pragma unroll
        for (int i = 0; i < 32; ++i) {
            const int c = grp * 32 + i;
            partials[(size_t)c * K1_WAVES + wid]        = wys[i];
            partials[(size_t)(64 + c) * K1_WAVES + wid] = wysq[i];
        }
    }
}

// ---------------------------------------------------------------------------
// K2: finalize BN stats; fold BN affine into the final conv weights/bias.
// One block per channel c.
// ---------------------------------------------------------------------------
__global__ __launch_bounds__(256)
void k2_stats(const float* __restrict__ partials,
              const float* __restrict__ Ww, const float* __restrict__ bw,
              const float* __restrict__ gamma, const float* __restrict__ beta,
              float* __restrict__ wws, float* __restrict__ bias2)
{
    __shared__ float red[256];
    const int c = blockIdx.x;
    const int t = threadIdx.x;

    float s = 0.f;
    for (int k = t; k < K1_WAVES; k += 256) s += partials[(size_t)c * K1_WAVES + k];
    red[t] = s; __syncthreads();
    for (int o = 128; o > 0; o >>= 1) { if (t < o) red[t] += red[t + o]; __syncthreads(); }
    const float S = red[0]; __syncthreads();

    float q = 0.f;
    for (int k = t; k < K1_WAVES; k += 256) q += partials[(size_t)(64 + c) * K1_WAVES + k];
    red[t] = q; __syncthreads();
    for (int o = 128; o > 0; o >>= 1) { if (t < o) red[t] += red[t + o]; __syncthreads(); }
    const float SS = red[0];

    const float invN = 1.0f / (float)NPOSN;
    const float mean = S * invN;
    const float var  = SS * invN - mean * mean;
    const float scale = gamma[c] * rsqrtf(var + 1e-5f);
    const float shift = beta[c] - mean * scale;
    if (t < 32) wws[c * 32 + t] = Ww[c * 32 + t] * scale;
    if (t == 0) bias2[c] = bw[c] * scale + shift;
}

// ---------------------------------------------------------------------------
// K3: out = (folded conv)(y) + x.  64 positions per block, coalesced.
// ---------------------------------------------------------------------------
__global__ __launch_bounds__(256)
void k3_out(const ushort_t* __restrict__ y,
            const float* __restrict__ wws, const float* __restrict__ bias2,
            const float* __restrict__ x, float* __restrict__ out)
{
    __shared__ float y_s[64][33];
    __shared__ float ww_s[64][32];
    __shared__ float b2_s[64];
    const int t = threadIdx.x;
    for (int idx = t; idx < 2048; idx += 256) ww_s[idx >> 5][idx & 31] = wws[idx];
    if (t < 64) b2_s[t] = bias2[t];

    const size_t pos0 = (size_t)blockIdx.x * 64;
    {
        const uint4 v = *reinterpret_cast<const uint4*>(y + pos0 * 32 + (size_t)t * 8);
        const int pl = t >> 2, e0 = (t & 3) * 8;
        const uint_t vv[4] = {v.x, v.y, v.z, v.w};
        #pragma unroll
        for (int k = 0; k < 4; ++k) {
            y_s[pl][e0 + 2*k]     = bf2f((ushort_t)(vv[k] & 0xffffu));
            y_s[pl][e0 + 2*k + 1] = bf2f((ushort_t)(vv[k] >> 16));
        }
    }
    __syncthreads();

    const int pl = t & 63;
    const int cg = t >> 6;
    const size_t pos = pos0 + pl;
    const size_t pix = pos >> 5;
    const int z   = (int)(pos & 31);
    const int pb  = (int)(pix >> 12);
    const int pw  = (int)((pix >> 6) & 63);
    const int phx = (int)(pix & 63);
    const size_t base = (size_t)pb * (Cc * WHZ) + (size_t)pw * HZ + (size_t)phx * Zd + (size_t)z;

    float yv[32];
    #pragma unroll
    for (int i = 0; i < 32; ++i) yv[i] = y_s[pl][i];

    #pragma unroll
    for (int i = 0; i < 16; ++i) {
        const int c = cg * 16 + i;
        float acc = b2_s[c];
        const float* wr = &ww_s[c][0];
        #pragma unroll
        for (int k = 0; k < 32; k += 4) {
            const float4 w4 = *reinterpret_cast<const float4*>(wr + k);
            acc = fmaf(w4.x, yv[k],   acc);
            acc = fmaf(w4.y, yv[k+1], acc);
            acc = fmaf(w4.z, yv[k+2], acc);
            acc = fmaf(w4.w, yv[k+3], acc);
        }
        const size_t off = base + (size_t)c * WHZ;
        out[off] = acc + x[off];
    }
}

// ---------------------------------------------------------------------------
extern "C" void kernel_launch(void* const* d_in, const int* in_sizes, int n_in,
                              void* d_out, int out_size, void* d_ws, size_t ws_size,
                              hipStream_t stream)
{
    const float* x     = (const float*)d_in[0];
    // d_in[1] = spacings (unused by reference)
    const float* Wg    = (const float*)d_in[2];
    const float* bg    = (const float*)d_in[3];
    const float* Wt    = (const float*)d_in[4];
    const float* bt    = (const float*)d_in[5];
    const float* Wp    = (const float*)d_in[6];
    const float* bp    = (const float*)d_in[7];
    const float* Ww    = (const float*)d_in[8];
    const float* bw    = (const float*)d_in[9];
    const float* gamma = (const float*)d_in[10];
    const float* beta  = (const float*)d_in[11];
    float* out = (float*)d_out;

    // Workspace layout
    ushort_t* y_ws   = (ushort_t*)d_ws;                                   // 64 MiB (bf16 y)
    float* partials  = (float*)((char*)d_ws + (size_t)33554432 * 2);      // 2 MiB
    float* wws       = (float*)((char*)partials + (size_t)128 * K1_WAVES * 4); // 8 KiB
    float* bias2     = wws + 2048;

    k1_attn<<<K1_BLK, 128, 0, stream>>>(x, Wg, bg, Wt, bt, Wp, bp, Ww, bw, y_ws, partials);
    k2_stats<<<64, 256, 0, stream>>>(partials, Ww, bw, gamma, beta, wws, bias2);
    k3_out<<<NPOSN / 64, 256, 0, stream>>>(y_ws, wws, bias2, x, out);
}

// Round 5
// 654.842 us; speedup vs baseline: 1.5065x; 1.3056x over previous
//
#include <hip/hip_runtime.h>

// Problem constants
#define Bb 8
#define Cc 64
#define ICc 32
#define Wd 64
#define Hd 64
#define Zd 32
#define WHZ 131072      // Wd*Hd*Zd
#define HZ 2048         // Hd*Zd
#define NPIXEL 32768    // Bb*Wd*Hd
#define NPOSN 1048576   // Bb*Wd*Hd*Zd
#define K1_BLK 2048
#define K1_WAVES 4096   // K1_BLK * 2 waves
#define NPIX 8          // pixels per wave

typedef unsigned short ushort_t;
typedef unsigned int uint_t;
typedef __attribute__((ext_vector_type(4))) float f32x4;
typedef short s8_a __attribute__((ext_vector_type(8), may_alias));       // 8 bf16 frag
typedef unsigned short u16_a __attribute__((may_alias));
typedef unsigned int u32x4_a __attribute__((ext_vector_type(4), may_alias));

__device__ __forceinline__ float bf2f(ushort_t u) {
    return __uint_as_float(((uint_t)u) << 16);
}
__device__ __forceinline__ ushort_t f2bf(float f) {
    uint_t x = __float_as_uint(f);
    uint_t r = (x + 0x7fffu + ((x >> 16) & 1u)) >> 16;  // round-to-nearest-even
    return (ushort_t)r;
}

// Compiler-only memory fence (zero instructions): orders LDS region re-use.
#define CFENCE() asm volatile("" ::: "memory")

// ---------------------------------------------------------------------------
// K1: per-pixel fused projections (MFMA) + attention (scalar) + wy stats (MFMA).
// B-fragments are read as contiguous 8-bf16 runs from z-major LDS panels —
// the m97-verified MFMA operand pattern (no ds_read_b64_tr_b16).
// Writes y (b,w,h,z,ic) as bf16, and per-wave partial sums of wy / wy^2.
// ---------------------------------------------------------------------------
__global__ __launch_bounds__(128)
void k1_attn(const float* __restrict__ x,
             const float* __restrict__ Wg, const float* __restrict__ bg,
             const float* __restrict__ Wt, const float* __restrict__ bt,
             const float* __restrict__ Wp, const float* __restrict__ bp,
             const float* __restrict__ Ww, const float* __restrict__ bw,
             ushort_t* __restrict__ y_out,
             float* __restrict__ partials)
{
    __shared__ ushort_t Wth[2048];   // [ic][c] bf16 (Wt is (32,64) row-major)
    __shared__ ushort_t Wph[2048];
    __shared__ ushort_t Wgg[2048];
    __shared__ ushort_t Wwb[2048];   // [c][ic] bf16 (Ww is (64,32) row-major)
    __shared__ float bt_s[32], bp_s[32], bg_s[32], bw_s[64];
    // Per-wave scratch, 2368 f32 = 9472 B, time-multiplexed:
    //  floats [0,1152)    : xt bf16 [32 z][72] (144B rows; proj B-operand)
    //                       then thf f32 [32][33] (after proj MFMAs)
    //                       then yt bf16 [32 z][40] (after softmax; wy B-operand)
    //  floats [1152,1792) : phf f32 [32][20]
    //  floats [1792,2368) : gpf f32 [16][36]
    __shared__ float pwz[2][2368];

    const int tid = threadIdx.x;
    for (int idx = tid; idx < 2048; idx += 128) {
        Wth[idx] = f2bf(Wt[idx]);
        Wph[idx] = f2bf(Wp[idx]);
        Wgg[idx] = f2bf(Wg[idx]);
        Wwb[idx] = f2bf(Ww[idx]);
    }
    if (tid < 32) { bt_s[tid] = bt[tid]; bp_s[tid] = bp[tid]; bg_s[tid] = bg[tid]; }
    if (tid < 64) bw_s[tid] = bw[tid];
    __syncthreads();   // weights shared by both waves; only block barrier

    const int lane = tid & 63;
    const int wv   = tid >> 6;
    const int wid  = blockIdx.x * 2 + wv;
    const int lq   = lane & 15;   // MFMA: A-row / B-col / D-col
    const int g    = lane >> 4;   // MFMA: k-group / D-row group
    const int zl   = lane & 31;   // attention-phase z
    const int grp  = lane >> 5;   // attention-phase half
    const int nz0  = grp * 8;

    float* const thf = &pwz[wv][0];
    float* const phf = &pwz[wv][1152];
    float* const gpf = &pwz[wv][1792];
    u16_a* const xt  = (u16_a*)&pwz[wv][0];   // [32][72] bf16
    u16_a* const yt  = (u16_a*)&pwz[wv][0];   // [32][40] bf16

    // --- Preload A-fragments (weights) into VGPRs, once ---
    // A-frag (16x16x32): lane holds A[lq + 16*mt][k0*32 + 8g + j], j=0..7 contiguous.
    s8_a aT[2][2], aP[2][2], aG[2][2], aW4[4];
    #pragma unroll
    for (int mt = 0; mt < 2; ++mt)
        #pragma unroll
        for (int k0 = 0; k0 < 2; ++k0) {
            const int off = (mt * 16 + lq) * 64 + k0 * 32 + g * 8;
            aT[mt][k0] = *(const s8_a*)&Wth[off];
            aP[mt][k0] = *(const s8_a*)&Wph[off];
            aG[mt][k0] = *(const s8_a*)&Wgg[off];
        }
    #pragma unroll
    for (int mt = 0; mt < 4; ++mt)
        aW4[mt] = *(const s8_a*)&Wwb[(mt * 16 + lq) * 32 + g * 8];

    // Per-lane bias registers (index mt*4+r -> channel mt*16 + 4g + r)
    float btv[8], bpv[8], bgv[8];
    #pragma unroll
    for (int i = 0; i < 8; ++i) {
        const int ic = (i >> 2) * 16 + 4 * g + (i & 3);
        btv[i] = bt_s[ic]; bpv[i] = bp_s[ic]; bgv[i] = bg_s[ic];
    }
    float bwv[16];
    #pragma unroll
    for (int i = 0; i < 16; ++i) bwv[i] = bw_s[(i >> 2) * 16 + 4 * g + (i & 3)];

    float wys[16], wysq[16];
    #pragma unroll
    for (int i = 0; i < 16; ++i) { wys[i] = 0.f; wysq[i] = 0.f; }

    const f32x4 zero4 = {0.f, 0.f, 0.f, 0.f};

    // Prime the x prefetch (pixel 0)
    float4 pf[8];
    {
        const int p = wid * NPIX;
        const size_t xb = (size_t)(p >> 12) * (Cc * WHZ) + (size_t)((p >> 6) & 63) * HZ
                        + (size_t)(p & 63) * Zd;
        #pragma unroll
        for (int k = 0; k < 8; ++k) {
            const int idx = k * 64 + lane;
            pf[k] = *reinterpret_cast<const float4*>(x + xb + (size_t)(idx >> 3) * WHZ + (idx & 7) * 4);
        }
    }

    for (int it = 0; it < NPIX; ++it) {
        const int p = wid * NPIX + it;

        // Phase 1: convert prefetched x to bf16, write z-major panel
        // xt[z][c^swz], swz = ((z>>2)&3)<<3 (spreads write banks; keeps 8-runs).
        CFENCE();
        #pragma unroll
        for (int k = 0; k < 8; ++k) {
            const int idx = k * 64 + lane;
            const int c = idx >> 3, q = idx & 7;       // thread holds z = 4q..4q+3
            const int cs = c ^ ((q & 3) << 3);          // z>>2 == q for all 4 elems
            const float vv[4] = {pf[k].x, pf[k].y, pf[k].z, pf[k].w};
            #pragma unroll
            for (int e = 0; e < 4; ++e)
                xt[(4 * q + e) * 72 + cs] = f2bf(vv[e]);
        }

        // Phase 2a: B-frags = contiguous 8-bf16 runs (ds_read_b128).
        // B[k=c][n=z]: elem (z=n0*16+lq, c-run at (k0*32+g*8)^swz), swz flips g.
        s8_a bx[2][2];
        {
            const int gx = (g ^ (lq >> 2)) * 8;
            #pragma unroll
            for (int k0 = 0; k0 < 2; ++k0)
                #pragma unroll
                for (int n0 = 0; n0 < 2; ++n0)
                    bx[k0][n0] = *(const s8_a*)&xt[(n0 * 16 + lq) * 72 + k0 * 32 + gx];
        }

        // Phase 2b: 24 MFMA -> D[ic][z] frags (col=lq -> z, row=4g+r -> ic)
        f32x4 dT[2][2], dP[2][2], dG[2][2];
        #pragma unroll
        for (int mt = 0; mt < 2; ++mt)
            #pragma unroll
            for (int n0 = 0; n0 < 2; ++n0) {
                dT[mt][n0] = __builtin_amdgcn_mfma_f32_16x16x32_bf16(
                    aT[mt][1], bx[1][n0],
                    __builtin_amdgcn_mfma_f32_16x16x32_bf16(aT[mt][0], bx[0][n0], zero4, 0, 0, 0),
                    0, 0, 0);
                dP[mt][n0] = __builtin_amdgcn_mfma_f32_16x16x32_bf16(
                    aP[mt][1], bx[1][n0],
                    __builtin_amdgcn_mfma_f32_16x16x32_bf16(aP[mt][0], bx[0][n0], zero4, 0, 0, 0),
                    0, 0, 0);
                dG[mt][n0] = __builtin_amdgcn_mfma_f32_16x16x32_bf16(
                    aG[mt][1], bx[1][n0],
                    __builtin_amdgcn_mfma_f32_16x16x32_bf16(aG[mt][0], bx[0][n0], zero4, 0, 0, 0),
                    0, 0, 0);
            }

        // Phase 3: scatter theta; pool phi/g over z-pairs (adjacent lanes) + scatter
        CFENCE();   // xt dead; thf overlays it
        #pragma unroll
        for (int mt = 0; mt < 2; ++mt)
            #pragma unroll
            for (int n0 = 0; n0 < 2; ++n0)
                #pragma unroll
                for (int r = 0; r < 4; ++r) {
                    const int ic = mt * 16 + 4 * g + r;
                    thf[ic * 33 + n0 * 16 + lq] = dT[mt][n0][r] + btv[mt * 4 + r];
                    float pv_ = dP[mt][n0][r];
                    pv_ = fmaxf(pv_, __shfl_xor(pv_, 1, 64));
                    phf[ic * 20 + n0 * 8 + (lq >> 1)] = pv_ + bpv[mt * 4 + r];
                    float gv_ = dG[mt][n0][r];
                    gv_ = fmaxf(gv_, __shfl_xor(gv_, 1, 64));
                    gpf[(n0 * 8 + (lq >> 1)) * 36 + ic] = gv_ + bgv[mt * 4 + r];
                }

        // Prefetch next pixel's x (latency hides under phases 4-6)
        {
            const int pn = wid * NPIX + ((it + 1) & 7);
            const size_t xb = (size_t)(pn >> 12) * (Cc * WHZ) + (size_t)((pn >> 6) & 63) * HZ
                            + (size_t)(pn & 63) * Zd;
            #pragma unroll
            for (int k = 0; k < 8; ++k) {
                const int idx = k * 64 + lane;
                pf[k] = *reinterpret_cast<const float4*>(x + xb + (size_t)(idx >> 3) * WHZ + (idx & 7) * 4);
            }
        }

        // Phase 4: f = theta^T @ phi (lane -> (z, nz-half)), softmax over nz
        float f[8];
        #pragma unroll
        for (int j = 0; j < 8; ++j) f[j] = 0.f;
        for (int i = 0; i < 32; ++i) {
            const float t = thf[i * 33 + zl];
            const float4 pa  = *reinterpret_cast<const float4*>(phf + i * 20 + nz0);
            const float4 pb4 = *reinterpret_cast<const float4*>(phf + i * 20 + nz0 + 4);
            f[0] = fmaf(t, pa.x,  f[0]); f[1] = fmaf(t, pa.y,  f[1]);
            f[2] = fmaf(t, pa.z,  f[2]); f[3] = fmaf(t, pa.w,  f[3]);
            f[4] = fmaf(t, pb4.x, f[4]); f[5] = fmaf(t, pb4.y, f[5]);
            f[6] = fmaf(t, pb4.z, f[6]); f[7] = fmaf(t, pb4.w, f[7]);
        }

        float m = f[0];
        #pragma unroll
        for (int j = 1; j < 8; ++j) m = fmaxf(m, f[j]);
        m = fmaxf(m, __shfl_xor(m, 32, 64));
        float ssum = 0.f;
        #pragma unroll
        for (int j = 0; j < 8; ++j) { f[j] = __expf(f[j] - m); ssum += f[j]; }
        ssum += __shfl_xor(ssum, 32, 64);
        const float rs = 1.0f / ssum;

        // Phase 5: y = P @ g  (halves hold 8 nz each -> xor-32 reduce)
        float y[32];
        #pragma unroll
        for (int i = 0; i < 32; ++i) y[i] = 0.f;
        #pragma unroll
        for (int j = 0; j < 8; ++j) {
            const float pj = f[j] * rs;
            const float* gr = gpf + (nz0 + j) * 36;
            #pragma unroll
            for (int i = 0; i < 32; i += 4) {
                const float4 g4 = *reinterpret_cast<const float4*>(gr + i);
                y[i]   = fmaf(pj, g4.x, y[i]);
                y[i+1] = fmaf(pj, g4.y, y[i+1]);
                y[i+2] = fmaf(pj, g4.z, y[i+2]);
                y[i+3] = fmaf(pj, g4.w, y[i+3]);
            }
        }
        #pragma unroll
        for (int i = 0; i < 32; ++i) y[i] += __shfl_xor(y[i], 32, 64);

        ushort_t yb[32];
        #pragma unroll
        for (int i = 0; i < 32; ++i) yb[i] = f2bf(y[i]);

        // Pack: lane (zl,grp) owns ic = grp*16..grp*16+15 (static idx + select)
        uint_t pk[8];
        #pragma unroll
        for (int i2 = 0; i2 < 8; ++i2) {
            const uint_t lo_ = (uint_t)yb[2*i2]      | ((uint_t)yb[2*i2+1]  << 16);
            const uint_t hi_ = (uint_t)yb[16 + 2*i2] | ((uint_t)yb[17 + 2*i2] << 16);
            pk[i2] = grp ? hi_ : lo_;
        }

        // Phase 5.5: stage y to z-major LDS panel yt[z][ic] (thf dead)
        CFENCE();
        {
            u32x4_a w0 = {pk[0], pk[1], pk[2], pk[3]};
            u32x4_a w1 = {pk[4], pk[5], pk[6], pk[7]};
            *(u32x4_a*)&yt[zl * 40 + grp * 16]     = w0;
            *(u32x4_a*)&yt[zl * 40 + grp * 16 + 8] = w1;
        }

        // Phase 6: store y (bf16) to global
        {
            uint4* dst = reinterpret_cast<uint4*>(y_out + ((size_t)p * 32 + zl) * 32 + grp * 16);
            dst[0] = make_uint4(pk[0], pk[1], pk[2], pk[3]);
            dst[1] = make_uint4(pk[4], pk[5], pk[6], pk[7]);
        }

        // Phase 7: wy = Ww @ y + bw via MFMA; accumulate stats from D-frags.
        // B[k=ic][n=z]: elem (z=n0*16+lq, ic-run at g*8) -> contiguous b128.
        s8_a by[2];
        by[0] = *(const s8_a*)&yt[lq * 40 + g * 8];
        by[1] = *(const s8_a*)&yt[(16 + lq) * 40 + g * 8];

        #pragma unroll
        for (int mt = 0; mt < 4; ++mt) {
            const f32x4 d0 = __builtin_amdgcn_mfma_f32_16x16x32_bf16(aW4[mt], by[0], zero4, 0, 0, 0);
            const f32x4 d1 = __builtin_amdgcn_mfma_f32_16x16x32_bf16(aW4[mt], by[1], zero4, 0, 0, 0);
            #pragma unroll
            for (int r = 0; r < 4; ++r) {
                const float a = d0[r] + bwv[mt * 4 + r];
                const float b = d1[r] + bwv[mt * 4 + r];
                wys[mt * 4 + r]  += a + b;
                wysq[mt * 4 + r] += a * a + b * b;
            }
        }
    }

    // Reduce stats over the 16 z-columns of each lane group (cols = lq)
    #pragma unroll
    for (int off = 1; off <= 8; off <<= 1) {
        #pragma unroll
        for (int i = 0; i < 16; ++i) {
            wys[i]  += __shfl_xor(wys[i],  off, 64);
            wysq[i] += __shfl_xor(wysq[i], off, 64);
        }
    }
    if (lq == 0) {
        #pragma unroll
        for (int i = 0; i < 16; ++i) {
            const int c = (i >> 2) * 16 + 4 * g + (i & 3);
            partials[(size_t)c * K1_WAVES + wid]        = wys[i];
            partials[(size_t)(64 + c) * K1_WAVES + wid] = wysq[i];
        }
    }
}

// ---------------------------------------------------------------------------
// K2: finalize BN stats; fold BN affine into the final conv weights/bias.
// ---------------------------------------------------------------------------
__global__ __launch_bounds__(256)
void k2_stats(const float* __restrict__ partials,
              const float* __restrict__ Ww, const float* __restrict__ bw,
              const float* __restrict__ gamma, const float* __restrict__ beta,
              float* __restrict__ wws, float* __restrict__ bias2)
{
    __shared__ float red[256];
    const int c = blockIdx.x;
    const int t = threadIdx.x;

    float s = 0.f;
    for (int k = t; k < K1_WAVES; k += 256) s += partials[(size_t)c * K1_WAVES + k];
    red[t] = s; __syncthreads();
    for (int o = 128; o > 0; o >>= 1) { if (t < o) red[t] += red[t + o]; __syncthreads(); }
    const float S = red[0]; __syncthreads();

    float q = 0.f;
    for (int k = t; k < K1_WAVES; k += 256) q += partials[(size_t)(64 + c) * K1_WAVES + k];
    red[t] = q; __syncthreads();
    for (int o = 128; o > 0; o >>= 1) { if (t < o) red[t] += red[t + o]; __syncthreads(); }
    const float SS = red[0];

    const float invN = 1.0f / (float)NPOSN;
    const float mean = S * invN;
    const float var  = SS * invN - mean * mean;
    const float scale = gamma[c] * rsqrtf(var + 1e-5f);
    const float shift = beta[c] - mean * scale;
    if (t < 32) wws[c * 32 + t] = Ww[c * 32 + t] * scale;
    if (t == 0) bias2[c] = bw[c] * scale + shift;
}

// ---------------------------------------------------------------------------
// K3: out = (folded conv)(y) + x.  64 positions per block, coalesced.
// ---------------------------------------------------------------------------
__global__ __launch_bounds__(256)
void k3_out(const ushort_t* __restrict__ y,
            const float* __restrict__ wws, const float* __restrict__ bias2,
            const float* __restrict__ x, float* __restrict__ out)
{
    __shared__ float y_s[64][33];
    __shared__ float ww_s[64][32];
    __shared__ float b2_s[64];
    const int t = threadIdx.x;
    for (int idx = t; idx < 2048; idx += 256) ww_s[idx >> 5][idx & 31] = wws[idx];
    if (t < 64) b2_s[t] = bias2[t];

    const size_t pos0 = (size_t)blockIdx.x * 64;
    {
        const uint4 v = *reinterpret_cast<const uint4*>(y + pos0 * 32 + (size_t)t * 8);
        const int pl = t >> 2, e0 = (t & 3) * 8;
        const uint_t vv[4] = {v.x, v.y, v.z, v.w};
        #pragma unroll
        for (int k = 0; k < 4; ++k) {
            y_s[pl][e0 + 2*k]     = bf2f((ushort_t)(vv[k] & 0xffffu));
            y_s[pl][e0 + 2*k + 1] = bf2f((ushort_t)(vv[k] >> 16));
        }
    }
    __syncthreads();

    const int pl = t & 63;
    const int cg = t >> 6;
    const size_t pos = pos0 + pl;
    const size_t pix = pos >> 5;
    const int z   = (int)(pos & 31);
    const int pb  = (int)(pix >> 12);
    const int pw  = (int)((pix >> 6) & 63);
    const int phx = (int)(pix & 63);
    const size_t base = (size_t)pb * (Cc * WHZ) + (size_t)pw * HZ + (size_t)phx * Zd + (size_t)z;

    float yv[32];
    #pragma unroll
    for (int i = 0; i < 32; ++i) yv[i] = y_s[pl][i];

    #pragma unroll
    for (int i = 0; i < 16; ++i) {
        const int c = cg * 16 + i;
        float acc = b2_s[c];
        const float* wr = &ww_s[c][0];
        #pragma unroll
        for (int k = 0; k < 32; k += 4) {
            const float4 w4 = *reinterpret_cast<const float4*>(wr + k);
            acc = fmaf(w4.x, yv[k],   acc);
            acc = fmaf(w4.y, yv[k+1], acc);
            acc = fmaf(w4.z, yv[k+2], acc);
            acc = fmaf(w4.w, yv[k+3], acc);
        }
        const size_t off = base + (size_t)c * WHZ;
        out[off] = acc + x[off];
    }
}

// ---------------------------------------------------------------------------
extern "C" void kernel_launch(void* const* d_in, const int* in_sizes, int n_in,
                              void* d_out, int out_size, void* d_ws, size_t ws_size,
                              hipStream_t stream)
{
    const float* x     = (const float*)d_in[0];
    // d_in[1] = spacings (unused by reference)
    const float* Wg    = (const float*)d_in[2];
    const float* bg    = (const float*)d_in[3];
    const float* Wt    = (const float*)d_in[4];
    const float* bt    = (const float*)d_in[5];
    const float* Wp    = (const float*)d_in[6];
    const float* bp    = (const float*)d_in[7];
    const float* Ww    = (const float*)d_in[8];
    const float* bw    = (const float*)d_in[9];
    const float* gamma = (const float*)d_in[10];
    const float* beta  = (const float*)d_in[11];
    float* out = (float*)d_out;

    // Workspace layout
    ushort_t* y_ws   = (ushort_t*)d_ws;                                   // 64 MiB (bf16 y)
    float* partials  = (float*)((char*)d_ws + (size_t)33554432 * 2);      // 2 MiB
    float* wws       = (float*)((char*)partials + (size_t)128 * K1_WAVES * 4); // 8 KiB
    float* bias2     = wws + 2048;

    k1_attn<<<K1_BLK, 128, 0, stream>>>(x, Wg, bg, Wt, bt, Wp, bp, Ww, bw, y_ws, partials);
    k2_stats<<<64, 256, 0, stream>>>(partials, Ww, bw, gamma, beta, wws, bias2);
    k3_out<<<NPOSN / 64, 256, 0, stream>>>(y_ws, wws, bias2, x, out);
}